// Round 16
// baseline (505.464 us; speedup 1.0000x reference)
//
#include <hip/hip_runtime.h>
#include <hip/hip_bf16.h>
#include <stdint.h>

#define D_EMBED 1024
#define D_HID   4096
#define N_TOK   4096
#define N_EXP   8
#define CAP     4096
#define NROWA   8448

typedef __attribute__((ext_vector_type(4))) float f32x4;
typedef __attribute__((ext_vector_type(8))) short bf16x8;

__device__ __forceinline__ unsigned short f2bf(float f) {
    unsigned int u = __builtin_bit_cast(unsigned int, f);
    u += 0x7fffu + ((u >> 16) & 1u);
    return (unsigned short)(u >> 16);
}
__device__ __forceinline__ float bf2f(unsigned short h) {
    unsigned int u = ((unsigned int)h) << 16;
    return __builtin_bit_cast(float, u);
}
__device__ __forceinline__ void gload_lds16(const void* g, void* l) {
    __builtin_amdgcn_global_load_lds(
        (const __attribute__((address_space(1))) unsigned int*)g,
        (__attribute__((address_space(3))) unsigned int*)l, 16, 0, 0);
}

// ---------------- gating ----------------
__global__ __launch_bounds__(256) void gate_kernel(const float* __restrict__ x,
                                                   const float* __restrict__ Wg,
                                                   int* __restrict__ counts,
                                                   int* __restrict__ toks,
                                                   float* __restrict__ wgts,
                                                   int* __restrict__ slots) {
    int wave = threadIdx.x >> 6;
    int lane = threadIdx.x & 63;
    int tok = blockIdx.x * 4 + wave;
    const float* xp = x + (size_t)tok * D_EMBED;
    float acc[8] = {0, 0, 0, 0, 0, 0, 0, 0};
#pragma unroll
    for (int i = 0; i < 16; ++i) {
        int d = lane + 64 * i;
        float xv = xp[d];
        f32x4 w0 = *reinterpret_cast<const f32x4*>(Wg + (size_t)d * 8);
        f32x4 w1 = *reinterpret_cast<const f32x4*>(Wg + (size_t)d * 8 + 4);
        acc[0] += xv * w0[0]; acc[1] += xv * w0[1]; acc[2] += xv * w0[2]; acc[3] += xv * w0[3];
        acc[4] += xv * w1[0]; acc[5] += xv * w1[1]; acc[6] += xv * w1[2]; acc[7] += xv * w1[3];
    }
#pragma unroll
    for (int e = 0; e < 8; ++e)
        for (int s = 32; s; s >>= 1) acc[e] += __shfl_xor(acc[e], s, 64);
    if (lane == 0) {
        int i0 = 0; float v0 = acc[0];
#pragma unroll
        for (int e = 1; e < 8; ++e) if (acc[e] > v0) { v0 = acc[e]; i0 = e; }
        int i1 = -1; float v1 = -1e30f;
#pragma unroll
        for (int e = 0; e < 8; ++e) if (e != i0 && acc[e] > v1) { v1 = acc[e]; i1 = e; }
        float ex = __expf(v1 - v0);
        float w0 = 1.0f / (1.0f + ex);
        float w1 = 1.0f - w0;
        int p0 = atomicAdd(&counts[i0], 1);
        toks[i0 * CAP + p0] = tok; wgts[i0 * CAP + p0] = w0; slots[i0 * CAP + p0] = 0;
        int p1 = atomicAdd(&counts[i1], 1);
        toks[i1 * CAP + p1] = tok; wgts[i1 * CAP + p1] = w1; slots[i1 * CAP + p1] = 1;
    }
}

// ------- gather x rows into compacted k-packed A (tok2row folded in) -------
__global__ __launch_bounds__(256) void gather_x_kernel(
    const float* __restrict__ x, const int* __restrict__ counts,
    const int* __restrict__ toks, const int* __restrict__ slots,
    int* __restrict__ tok2row, unsigned short* __restrict__ xg) {
    int rt = blockIdx.x;
    int e = -1, tb = 0, osum = 0, rowbase = 0, cnt = 0, off = 0;
    for (int ee = 0; ee < N_EXP; ++ee) {
        int c = counts[ee];
        int nt = (c + 63) >> 6;
        if (rt < tb + nt) { e = ee; rowbase = (rt - tb) << 6; cnt = c; off = osum; break; }
        tb += nt; osum += c;
    }
    if (e < 0) return;
    int kb = blockIdx.y;
    int t = threadIdx.x;
    if (kb == 0 && t < 64) {
        int pos = rowbase + t;
        if (pos < cnt) {
            int i = e * CAP + pos;
            tok2row[toks[i] * 2 + slots[i]] = off + pos;
        }
    }
    __shared__ unsigned short lds[64][72];
    int r = t >> 2, ck = t & 3;
    int pos = rowbase + r;
    unsigned short tmp[16];
    if (pos < cnt) {
        int tok = toks[e * CAP + pos];
        const float* src = x + (size_t)tok * D_EMBED + kb * 64 + ck * 16;
#pragma unroll
        for (int i = 0; i < 4; ++i) {
            f32x4 v = *reinterpret_cast<const f32x4*>(src + i * 4);
#pragma unroll
            for (int j = 0; j < 4; ++j) tmp[i * 4 + j] = f2bf(v[j]);
        }
    } else {
#pragma unroll
        for (int i = 0; i < 16; ++i) tmp[i] = 0;
    }
#pragma unroll
    for (int i = 0; i < 16; ++i) lds[r][ck * 16 + i] = tmp[i];
    __syncthreads();
    int sl = t >> 5, rr = (t & 31) * 2;
#pragma unroll
    for (int w = 0; w < 2; ++w) {
        int rw = rr + w;
        if (rowbase + rw >= cnt) continue;
        bf16x8 o;
#pragma unroll
        for (int j = 0; j < 8; ++j) o[j] = (short)lds[rw][sl * 8 + j];
        *reinterpret_cast<bf16x8*>(xg + ((size_t)(kb * 8 + sl) * NROWA + off + rowbase + rw) * 8) = o;
    }
}

// ======= GEMM1: 128x128p; A ring-3 (gload); B = fused f32->bf16, col-owner staging =======
// thread owns col pc=t&127, slices {t>>7, t>>7+2}: 16 coalesced scalar loads,
// 2x bf16x8 ds_write at lane-contiguous 16B cells -> 0 bank conflicts.
// grid (x = packed coltile 64, y = rowtile 72): XCD = x%8 -> B panel pinned per XCD
__global__ __launch_bounds__(256, 3) void gemm1_kernel(
    const unsigned short* __restrict__ xg,
    const float* __restrict__ W1,
    const float* __restrict__ W3,
    const int* __restrict__ counts,
    const float* __restrict__ wgts,
    unsigned short* __restrict__ hp) {
    int rt = blockIdx.y;
    int e = -1, tb = 0, osum = 0, rowbase = 0, cnt = 0, off = 0;
#pragma unroll 1
    for (int ee = 0; ee < N_EXP; ++ee) {
        int c = counts[ee];
        int nt = (c + 127) >> 7;
        if (rt < tb + nt) { e = ee; rowbase = (rt - tb) << 7; cnt = c; off = osum; break; }
        tb += nt; osum += c;
    }
    if (e < 0) return;

    __shared__ __align__(16) char lds[40960];      // A: 3 x 8K @0 | B: 2 x 8K @24576

    int t = threadIdx.x, lane = t & 63, w = t >> 6;   // 4 waves, 2Mx2N
    int wr = w >> 1, wc = w & 1;
    int q = lane >> 4, p = lane & 15;

    // ---- A staging (gload_lds, 2/thread/step) ----
    const size_t ASTEP = (size_t)4 * NROWA * 16;
    const size_t A2 = (size_t)2 * NROWA * 16;
    const char* aS = (const char*)xg + ((size_t)(t >> 7) * NROWA + off + rowbase + (t & 127)) * 16;

    // ---- B staging: col-owner fused conversion ----
    int pc = t & 127;                       // owned packed col within tile
    int s0 = t >> 7;                        // first owned slice (0/1); also owns s0+2
    int PC = blockIdx.x * 128 + pc;
    int g  = PC >> 4;
    int rcg = ((g >> 1) << 4) | (PC & 15);
    const float* bP = ((g & 1) ? W3 : W1) + (size_t)e * (D_EMBED * D_HID)
                    + (size_t)(s0 * 8) * D_HID + rcg;
    int wrel0 = (s0 * 128 + pc) * 16;       // byte offsets of the two owned 16B cells
    int wrel1 = ((s0 + 2) * 128 + pc) * 16;

    float vb[16];
    int aw = 0, bw = 0;
    auto BLOAD = [&]() {
#pragma unroll
        for (int i = 0; i < 2; ++i)
#pragma unroll
            for (int j = 0; j < 8; ++j)
                vb[i * 8 + j] = bP[(size_t)(16 * i + j) * D_HID];
        bP += (size_t)32 * D_HID;
    };
    auto BWRITE = [&]() {
        char* L = lds + 24576 + bw * 8192; bw ^= 1;
        bf16x8 o0, o1;
#pragma unroll
        for (int j = 0; j < 8; ++j) { o0[j] = (short)f2bf(vb[j]); o1[j] = (short)f2bf(vb[8 + j]); }
        *reinterpret_cast<bf16x8*>(L + wrel0) = o0;
        *reinterpret_cast<bf16x8*>(L + wrel1) = o1;
    };
    auto AGLOAD = [&]() {
        char* L = lds + aw * 8192; aw = (aw == 2) ? 0 : aw + 1;
        gload_lds16(aS, L + t * 16);
        gload_lds16(aS + A2, L + 4096 + t * 16);
        aS += ASTEP;
    };

    f32x4 acc[4][4] = {};

    // prologue: B0 regs; A0; write B0 (implicit vb wait); B1 regs; A1
    BLOAD(); AGLOAD();
    BWRITE();
    BLOAD(); AGLOAD();
    int ar = 0;
#pragma unroll 1
    for (int h = 0; h < 32; ++h) {                 // K=1024, half-K=32
        if (h < 31) asm volatile("s_waitcnt vmcnt(18)" ::: "memory");  // A(h) landed
        else        asm volatile("s_waitcnt vmcnt(0)" ::: "memory");
        asm volatile("s_waitcnt lgkmcnt(0)" ::: "memory");             // B(h) writes done
        __builtin_amdgcn_s_barrier();
        __builtin_amdgcn_sched_barrier(0);
        const char* LA = lds + ar * 8192; ar = (ar == 2) ? 0 : ar + 1;
        const char* LB = lds + 24576 + (h & 1) * 8192;
        bf16x8 af[4], bf[4];
#pragma unroll
        for (int m = 0; m < 4; ++m)
            af[m] = *reinterpret_cast<const bf16x8*>(LA + (q * 128 + wr * 64 + m * 16 + p) * 16);
#pragma unroll
        for (int n = 0; n < 4; ++n)
            bf[n] = *reinterpret_cast<const bf16x8*>(LB + (q * 128 + wc * 64 + n * 16 + p) * 16);
        __builtin_amdgcn_s_setprio(1);
#pragma unroll
        for (int n = 0; n < 4; ++n)
#pragma unroll
            for (int m = 0; m < 4; ++m)
                acc[m][n] = __builtin_amdgcn_mfma_f32_16x16x32_bf16(af[m], bf[n], acc[m][n], 0, 0, 0);
        __builtin_amdgcn_s_setprio(0);
        // post-barrier staging: targets' readers all passed barrier(h)
        if (h < 31) BWRITE();                      // B(h+1) -> Bslot (h+1)&1 (vb loaded last iter)
        if (h < 30) { BLOAD(); AGLOAD(); }         // B(h+2) regs; A(h+2) -> Aslot (h+2)%3
    }

    // epilogue: (even n = W1, odd n = W3) -> SwiGLU * gate-weight -> hp (k-packed)
#pragma unroll
    for (int m = 0; m < 4; ++m) {
#pragma unroll
        for (int reg = 0; reg < 4; ++reg) {
            int rl = wr * 64 + m * 16 + q * 4 + reg;
            int grow = rowbase + rl;
            if (grow >= cnt) continue;
            float wgt = wgts[e * CAP + grow];
            size_t row = (size_t)(off + grow);
#pragma unroll
            for (int np = 0; np < 2; ++np) {
                float a1 = acc[m][2 * np][reg];
                float a3 = acc[m][2 * np + 1][reg];
                float hv = (a1 / (1.0f + __expf(-a1))) * a3 * wgt;
                int rcw = (blockIdx.x * 4 + wc * 2 + np) * 16 + p;
                hp[((size_t)(rcw >> 3) * NROWA + row) * 8 + (rcw & 7)] = f2bf(hv);
            }
        }
    }
}

// ======= GEMM2: 128x128, split-K=4; A ring-3, B = fused f32 W2 col-owner staging =======
// grid (x = coltile 8, y = rowtile 72, z = split 4): XCD = x -> B col panel pinned
__global__ __launch_bounds__(256, 3) void gemm2_kernel(
    const unsigned short* __restrict__ hp,
    const float* __restrict__ W2,
    const int* __restrict__ counts,
    unsigned short* __restrict__ pbuf) {
    int rt = blockIdx.y;
    int e = -1, tb = 0, osum = 0, rowbase = 0, cnt = 0, off = 0;
#pragma unroll 1
    for (int ee = 0; ee < N_EXP; ++ee) {
        int c = counts[ee];
        int nt = (c + 127) >> 7;
        if (rt < tb + nt) { e = ee; rowbase = (rt - tb) << 7; cnt = c; off = osum; break; }
        tb += nt; osum += c;
    }
    if (e < 0) return;
    int s2 = blockIdx.z;

    __shared__ __align__(16) char lds[40960];

    int t = threadIdx.x, lane = t & 63, w = t >> 6;
    int wr = w >> 1, wc = w & 1;
    int q = lane >> 4, p = lane & 15;

    const size_t ASTEP = (size_t)4 * NROWA * 16;
    const size_t A2 = (size_t)2 * NROWA * 16;
    const char* aS = (const char*)hp
        + ((size_t)(s2 * 128 + (t >> 7)) * NROWA + off + rowbase + (t & 127)) * 16;

    int pc = t & 127;
    int s0 = t >> 7;
    const float* bP = W2 + (size_t)e * (D_HID * D_EMBED)
                    + (size_t)(s2 * 1024 + s0 * 8) * D_EMBED + blockIdx.x * 128 + pc;
    int wrel0 = (s0 * 128 + pc) * 16;
    int wrel1 = ((s0 + 2) * 128 + pc) * 16;

    float vb[16];
    int aw = 0, bw = 0;
    auto BLOAD = [&]() {
#pragma unroll
        for (int i = 0; i < 2; ++i)
#pragma unroll
            for (int j = 0; j < 8; ++j)
                vb[i * 8 + j] = bP[(size_t)(16 * i + j) * D_EMBED];
        bP += (size_t)32 * D_EMBED;
    };
    auto BWRITE = [&]() {
        char* L = lds + 24576 + bw * 8192; bw ^= 1;
        bf16x8 o0, o1;
#pragma unroll
        for (int j = 0; j < 8; ++j) { o0[j] = (short)f2bf(vb[j]); o1[j] = (short)f2bf(vb[8 + j]); }
        *reinterpret_cast<bf16x8*>(L + wrel0) = o0;
        *reinterpret_cast<bf16x8*>(L + wrel1) = o1;
    };
    auto AGLOAD = [&]() {
        char* L = lds + aw * 8192; aw = (aw == 2) ? 0 : aw + 1;
        gload_lds16(aS, L + t * 16);
        gload_lds16(aS + A2, L + 4096 + t * 16);
        aS += ASTEP;
    };

    f32x4 acc[4][4] = {};

    BLOAD(); AGLOAD();
    BWRITE();
    BLOAD(); AGLOAD();
    int ar = 0;
#pragma unroll 1
    for (int h = 0; h < 32; ++h) {                 // 1024 k per split, half-K=32
        if (h < 31) asm volatile("s_waitcnt vmcnt(18)" ::: "memory");
        else        asm volatile("s_waitcnt vmcnt(0)" ::: "memory");
        asm volatile("s_waitcnt lgkmcnt(0)" ::: "memory");
        __builtin_amdgcn_s_barrier();
        __builtin_amdgcn_sched_barrier(0);
        const char* LA = lds + ar * 8192; ar = (ar == 2) ? 0 : ar + 1;
        const char* LB = lds + 24576 + (h & 1) * 8192;
        bf16x8 af[4], bf[4];
#pragma unroll
        for (int m = 0; m < 4; ++m)
            af[m] = *reinterpret_cast<const bf16x8*>(LA + (q * 128 + wr * 64 + m * 16 + p) * 16);
#pragma unroll
        for (int n = 0; n < 4; ++n)
            bf[n] = *reinterpret_cast<const bf16x8*>(LB + (q * 128 + wc * 64 + n * 16 + p) * 16);
        __builtin_amdgcn_s_setprio(1);
#pragma unroll
        for (int n = 0; n < 4; ++n)
#pragma unroll
            for (int m = 0; m < 4; ++m)
                acc[m][n] = __builtin_amdgcn_mfma_f32_16x16x32_bf16(af[m], bf[n], acc[m][n], 0, 0, 0);
        __builtin_amdgcn_s_setprio(0);
        if (h < 31) BWRITE();
        if (h < 30) { BLOAD(); AGLOAD(); }
    }

    unsigned short* pb = pbuf + (size_t)s2 * 8192 * D_EMBED;
#pragma unroll
    for (int m = 0; m < 4; ++m)
#pragma unroll
        for (int reg = 0; reg < 4; ++reg) {
            int rl = wr * 64 + m * 16 + q * 4 + reg;
            int grow = rowbase + rl;
            if (grow >= cnt) continue;
            unsigned short* dst = pb + (size_t)(off + grow) * D_EMBED + blockIdx.x * 128 + wc * 64;
#pragma unroll
            for (int n = 0; n < 4; ++n) dst[n * 16 + p] = f2bf(acc[m][n][reg]);
        }
}

// ---------------- combine: out[tok] = sum over 2 rows x 4 k-splits (bf16 pbuf) ----------------
__global__ __launch_bounds__(256) void combine_kernel(const unsigned short* __restrict__ pbuf,
                                                      const int* __restrict__ tok2row,
                                                      float* __restrict__ out) {
    int i = blockIdx.x * 256 + threadIdx.x;        // N_TOK * 128, 8 cols each
    int tok = i >> 7, c0 = (i & 127) * 8;
    int r0 = tok2row[tok * 2], r1 = tok2row[tok * 2 + 1];
    const size_t SP = (size_t)8192 * D_EMBED;
    float s[8] = {0, 0, 0, 0, 0, 0, 0, 0};
#pragma unroll
    for (int sp = 0; sp < 4; ++sp) {
        bf16x8 a = *reinterpret_cast<const bf16x8*>(pbuf + sp * SP + (size_t)r0 * D_EMBED + c0);
        bf16x8 b = *reinterpret_cast<const bf16x8*>(pbuf + sp * SP + (size_t)r1 * D_EMBED + c0);
#pragma unroll
        for (int j = 0; j < 8; ++j)
            s[j] += bf2f((unsigned short)a[j]) + bf2f((unsigned short)b[j]);
    }
    float* op = out + (size_t)tok * D_EMBED + c0;
    f32x4 lo = {s[0], s[1], s[2], s[3]}, hi = {s[4], s[5], s[6], s[7]};
    *reinterpret_cast<f32x4*>(op) = lo;
    *reinterpret_cast<f32x4*>(op + 4) = hi;
}

extern "C" void kernel_launch(void* const* d_in, const int* in_sizes, int n_in,
                              void* d_out, int out_size, void* d_ws, size_t ws_size,
                              hipStream_t stream) {
    const float* x  = (const float*)d_in[0];
    const float* Wg = (const float*)d_in[1];
    const float* W1 = (const float*)d_in[2];
    const float* W3 = (const float*)d_in[3];
    const float* W2 = (const float*)d_in[4];
    float* out = (float*)d_out;

    char* ws = (char*)d_ws;
    unsigned short* pbuf = (unsigned short*)ws; ws += (size_t)4 * 8192 * D_EMBED * 2;  // 64 MB
    unsigned short* hp   = (unsigned short*)ws; ws += (size_t)(D_HID / 8) * NROWA * 8 * 2;
    unsigned short* xg   = (unsigned short*)ws; ws += (size_t)(D_EMBED / 8) * NROWA * 8 * 2;
    int*   toks    = (int*)ws;   ws += (size_t)N_EXP * CAP * 4;
    float* wgts    = (float*)ws; ws += (size_t)N_EXP * CAP * 4;
    int*   slots   = (int*)ws;   ws += (size_t)N_EXP * CAP * 4;
    int*   tok2row = (int*)ws;   ws += (size_t)N_TOK * 2 * 4;
    int*   counts  = (int*)ws;   ws += 8 * 4;

    hipMemsetAsync(counts, 0, 8 * sizeof(int), stream);

    gate_kernel<<<N_TOK / 4, 256, 0, stream>>>(x, Wg, counts, toks, wgts, slots);
    gather_x_kernel<<<dim3(136, D_EMBED / 64), 256, 0, stream>>>(x, counts, toks, slots, tok2row, xg);
    gemm1_kernel<<<dim3(64, 72), 256, 0, stream>>>(xg, W1, W3, counts, wgts, hp);
    gemm2_kernel<<<dim3(8, 72, 4), 256, 0, stream>>>(hp, W2, counts, pbuf);
    combine_kernel<<<(N_TOK * 128) / 256, 256, 0, stream>>>(pbuf, tok2row, out);
}

// Round 17
// 485.811 us; speedup vs baseline: 1.0405x; 1.0405x over previous
//
#include <hip/hip_runtime.h>
#include <hip/hip_bf16.h>
#include <stdint.h>

#define D_EMBED 1024
#define D_HID   4096
#define N_TOK   4096
#define N_EXP   8
#define CAP     4096
#define NROWA   8448

typedef __attribute__((ext_vector_type(4))) float f32x4;
typedef __attribute__((ext_vector_type(8))) short bf16x8;

__device__ __forceinline__ unsigned short f2bf(float f) {
    unsigned int u = __builtin_bit_cast(unsigned int, f);
    u += 0x7fffu + ((u >> 16) & 1u);
    return (unsigned short)(u >> 16);
}
__device__ __forceinline__ float bf2f(unsigned short h) {
    unsigned int u = ((unsigned int)h) << 16;
    return __builtin_bit_cast(float, u);
}
__device__ __forceinline__ void gload_lds16(const void* g, void* l) {
    __builtin_amdgcn_global_load_lds(
        (const __attribute__((address_space(1))) unsigned int*)g,
        (__attribute__((address_space(3))) unsigned int*)l, 16, 0, 0);
}

// ======= merged: vectorized weight pack + gating, one launch =======
// blocks [0,8192): wt13.  [8192,12288): wt2.  [12288,13312): gate.
__global__ __launch_bounds__(256) void pack_gate_v(const float* __restrict__ W1,
                                                   const float* __restrict__ W3,
                                                   const float* __restrict__ W2,
                                                   const float* __restrict__ x,
                                                   const float* __restrict__ Wg,
                                                   unsigned short* __restrict__ wt13,
                                                   unsigned short* __restrict__ wt2,
                                                   int* __restrict__ counts,
                                                   int* __restrict__ toks,
                                                   float* __restrict__ wgts,
                                                   int* __restrict__ slots) {
    int b = blockIdx.x;
    if (b < 8192) {
        int idx = b * 256 + threadIdx.x;            // 2^21
        int pc0 = (idx & 2047) * 4;                 // packed col, 4 per thread
        int s   = (idx >> 11) & 127;                // k-slice
        int e   = idx >> 18;
        int g = pc0 >> 4;
        int rc0 = ((g >> 1) << 4) + (pc0 & 15);
        const float* src = (g & 1 ? W3 : W1) + (size_t)e * (D_EMBED * D_HID)
                         + (size_t)(s * 8) * D_HID + rc0;
        f32x4 v[8];
#pragma unroll
        for (int j = 0; j < 8; ++j)
            v[j] = *reinterpret_cast<const f32x4*>(src + (size_t)j * D_HID);
        unsigned short* dst = wt13 + (size_t)e * (D_EMBED * 2 * D_HID)
                            + ((size_t)s * (2 * D_HID) + pc0) * 8;
#pragma unroll
        for (int c = 0; c < 4; ++c) {
            bf16x8 o;
#pragma unroll
            for (int j = 0; j < 8; ++j) o[j] = (short)f2bf(v[j][c]);
            *reinterpret_cast<bf16x8*>(dst + c * 8) = o;
        }
    } else if (b < 12288) {
        int idx = (b - 8192) * 256 + threadIdx.x;   // 2^20
        int col0 = (idx & 255) * 4;
        int s    = (idx >> 8) & 511;
        int e    = idx >> 17;
        const float* src = W2 + (size_t)e * (D_HID * D_EMBED)
                         + (size_t)(s * 8) * D_EMBED + col0;
        f32x4 v[8];
#pragma unroll
        for (int j = 0; j < 8; ++j)
            v[j] = *reinterpret_cast<const f32x4*>(src + (size_t)j * D_EMBED);
        unsigned short* dst = wt2 + (size_t)e * (D_HID * D_EMBED)
                            + ((size_t)s * D_EMBED + col0) * 8;
#pragma unroll
        for (int c = 0; c < 4; ++c) {
            bf16x8 o;
#pragma unroll
            for (int j = 0; j < 8; ++j) o[j] = (short)f2bf(v[j][c]);
            *reinterpret_cast<bf16x8*>(dst + c * 8) = o;
        }
    } else {
        int gb = b - 12288;
        int wave = threadIdx.x >> 6;
        int lane = threadIdx.x & 63;
        int tok = gb * 4 + wave;
        const float* xp = x + (size_t)tok * D_EMBED;
        float acc[8] = {0, 0, 0, 0, 0, 0, 0, 0};
#pragma unroll
        for (int i = 0; i < 16; ++i) {
            int d = lane + 64 * i;
            float xv = xp[d];
            f32x4 w0 = *reinterpret_cast<const f32x4*>(Wg + (size_t)d * 8);
            f32x4 w1 = *reinterpret_cast<const f32x4*>(Wg + (size_t)d * 8 + 4);
            acc[0] += xv * w0[0]; acc[1] += xv * w0[1]; acc[2] += xv * w0[2]; acc[3] += xv * w0[3];
            acc[4] += xv * w1[0]; acc[5] += xv * w1[1]; acc[6] += xv * w1[2]; acc[7] += xv * w1[3];
        }
#pragma unroll
        for (int e = 0; e < 8; ++e)
            for (int s = 32; s; s >>= 1) acc[e] += __shfl_xor(acc[e], s, 64);
        if (lane == 0) {
            int i0 = 0; float v0 = acc[0];
#pragma unroll
            for (int e = 1; e < 8; ++e) if (acc[e] > v0) { v0 = acc[e]; i0 = e; }
            int i1 = -1; float v1 = -1e30f;
#pragma unroll
            for (int e = 0; e < 8; ++e) if (e != i0 && acc[e] > v1) { v1 = acc[e]; i1 = e; }
            float ex = __expf(v1 - v0);
            float w0 = 1.0f / (1.0f + ex);
            float w1 = 1.0f - w0;
            int p0 = atomicAdd(&counts[i0], 1);
            toks[i0 * CAP + p0] = tok; wgts[i0 * CAP + p0] = w0; slots[i0 * CAP + p0] = 0;
            int p1 = atomicAdd(&counts[i1], 1);
            toks[i1 * CAP + p1] = tok; wgts[i1 * CAP + p1] = w1; slots[i1 * CAP + p1] = 1;
        }
    }
}

// ------- gather x rows into compacted k-packed A (tok2row folded in) -------
__global__ __launch_bounds__(256) void gather_x_kernel(
    const float* __restrict__ x, const int* __restrict__ counts,
    const int* __restrict__ toks, const int* __restrict__ slots,
    int* __restrict__ tok2row, unsigned short* __restrict__ xg) {
    int rt = blockIdx.x;
    int e = -1, tb = 0, osum = 0, rowbase = 0, cnt = 0, off = 0;
    for (int ee = 0; ee < N_EXP; ++ee) {
        int c = counts[ee];
        int nt = (c + 63) >> 6;
        if (rt < tb + nt) { e = ee; rowbase = (rt - tb) << 6; cnt = c; off = osum; break; }
        tb += nt; osum += c;
    }
    if (e < 0) return;
    int kb = blockIdx.y;
    int t = threadIdx.x;
    if (kb == 0 && t < 64) {
        int pos = rowbase + t;
        if (pos < cnt) {
            int i = e * CAP + pos;
            tok2row[toks[i] * 2 + slots[i]] = off + pos;
        }
    }
    __shared__ unsigned short lds[64][72];
    int r = t >> 2, ck = t & 3;
    int pos = rowbase + r;
    unsigned short tmp[16];
    if (pos < cnt) {
        int tok = toks[e * CAP + pos];
        const float* src = x + (size_t)tok * D_EMBED + kb * 64 + ck * 16;
#pragma unroll
        for (int i = 0; i < 4; ++i) {
            f32x4 v = *reinterpret_cast<const f32x4*>(src + i * 4);
#pragma unroll
            for (int j = 0; j < 4; ++j) tmp[i * 4 + j] = f2bf(v[j]);
        }
    } else {
#pragma unroll
        for (int i = 0; i < 16; ++i) tmp[i] = 0;
    }
#pragma unroll
    for (int i = 0; i < 16; ++i) lds[r][ck * 16 + i] = tmp[i];
    __syncthreads();
    int sl = t >> 5, rr = (t & 31) * 2;
#pragma unroll
    for (int w = 0; w < 2; ++w) {
        int rw = rr + w;
        if (rowbase + rw >= cnt) continue;
        bf16x8 o;
#pragma unroll
        for (int j = 0; j < 8; ++j) o[j] = (short)lds[rw][sl * 8 + j];
        *reinterpret_cast<bf16x8*>(xg + ((size_t)(kb * 8 + sl) * NROWA + off + rowbase + rw) * 8) = o;
    }
}

// ======= GEMM1: 128x128p, 4 waves (2Mx2N), ring-2 half-K(32), vmcnt(4) =======
// grid (x = packed coltile 64, y = rowtile 72): XCD = x%8 -> B panel pinned per XCD
__global__ __launch_bounds__(256, 4) void gemm1_kernel(
    const unsigned short* __restrict__ xg,
    const unsigned short* __restrict__ wt13,
    const int* __restrict__ counts,
    const float* __restrict__ wgts,
    unsigned short* __restrict__ hp) {
    int rt = blockIdx.y;
    int e = -1, tb = 0, osum = 0, rowbase = 0, cnt = 0, off = 0;
#pragma unroll 1
    for (int ee = 0; ee < N_EXP; ++ee) {
        int c = counts[ee];
        int nt = (c + 127) >> 7;
        if (rt < tb + nt) { e = ee; rowbase = (rt - tb) << 7; cnt = c; off = osum; break; }
        tb += nt; osum += c;
    }
    if (e < 0) return;

    __shared__ __align__(16) char lds[2][16384];   // slot: A 8K | B 8K

    int t = threadIdx.x, lane = t & 63, w = t >> 6;   // 4 waves, 2Mx2N
    int wr = w >> 1, wc = w & 1;
    int q = lane >> 4, p = lane & 15;

    const size_t ASTEP = (size_t)4 * NROWA * 16;
    const size_t BSTEP = (size_t)4 * (2 * D_HID) * 16;
    const size_t A2 = (size_t)2 * NROWA * 16;
    const size_t B2 = (size_t)2 * (2 * D_HID) * 16;
    const char* aS = (const char*)xg + ((size_t)(t >> 7) * NROWA + off + rowbase + (t & 127)) * 16;
    const char* bS = (const char*)wt13 + (size_t)e * D_EMBED * 2 * D_HID * 2
                   + ((size_t)(t >> 7) * (2 * D_HID) + blockIdx.x * 128 + (t & 127)) * 16;

    int wslot = 0;
    auto STG = [&]() {
        char* L = &lds[wslot][0];
        wslot ^= 1;
        gload_lds16(aS, L + t * 16);
        gload_lds16(aS + A2, L + 4096 + t * 16);
        gload_lds16(bS, L + 8192 + t * 16);
        gload_lds16(bS + B2, L + 12288 + t * 16);
        aS += ASTEP; bS += BSTEP;
    };

    f32x4 acc[4][4] = {};

    STG();
#pragma unroll 1
    for (int h = 0; h < 32; ++h) {                 // K=1024, half-K=32
        if (h < 31) STG();
        if (h < 31) asm volatile("s_waitcnt vmcnt(4)" ::: "memory");
        else        asm volatile("s_waitcnt vmcnt(0)" ::: "memory");
        __builtin_amdgcn_s_barrier();
        __builtin_amdgcn_sched_barrier(0);
        const char* L = &lds[h & 1][0];
        bf16x8 af[4], bf[4];
#pragma unroll
        for (int m = 0; m < 4; ++m)
            af[m] = *reinterpret_cast<const bf16x8*>(L + (q * 128 + wr * 64 + m * 16 + p) * 16);
#pragma unroll
        for (int n = 0; n < 4; ++n)
            bf[n] = *reinterpret_cast<const bf16x8*>(L + 8192 + (q * 128 + wc * 64 + n * 16 + p) * 16);
        __builtin_amdgcn_s_setprio(1);
#pragma unroll
        for (int n = 0; n < 4; ++n)
#pragma unroll
            for (int m = 0; m < 4; ++m)
                acc[m][n] = __builtin_amdgcn_mfma_f32_16x16x32_bf16(af[m], bf[n], acc[m][n], 0, 0, 0);
        __builtin_amdgcn_s_setprio(0);
    }

    // epilogue: (even n = W1, odd n = W3) -> SwiGLU * gate-weight -> hp (k-packed)
#pragma unroll
    for (int m = 0; m < 4; ++m) {
#pragma unroll
        for (int reg = 0; reg < 4; ++reg) {
            int rl = wr * 64 + m * 16 + q * 4 + reg;
            int grow = rowbase + rl;
            if (grow >= cnt) continue;
            float wgt = wgts[e * CAP + grow];
            size_t row = (size_t)(off + grow);
#pragma unroll
            for (int np = 0; np < 2; ++np) {
                float a1 = acc[m][2 * np][reg];
                float a3 = acc[m][2 * np + 1][reg];
                float hv = (a1 / (1.0f + __expf(-a1))) * a3 * wgt;
                int rc = (blockIdx.x * 4 + wc * 2 + np) * 16 + p;
                hp[((size_t)(rc >> 3) * NROWA + row) * 8 + (rc & 7)] = f2bf(hv);
            }
        }
    }
}

// ======= GEMM2: 128x128, 4 waves, split-K=4, ring-2 vmcnt(4) =======
// grid (x = coltile 8, y = rowtile 72, z = split 4): XCD = x -> B col panel pinned
__global__ __launch_bounds__(256, 4) void gemm2_kernel(
    const unsigned short* __restrict__ hp,
    const unsigned short* __restrict__ wt2,
    const int* __restrict__ counts,
    unsigned short* __restrict__ pbuf) {
    int rt = blockIdx.y;
    int e = -1, tb = 0, osum = 0, rowbase = 0, cnt = 0, off = 0;
#pragma unroll 1
    for (int ee = 0; ee < N_EXP; ++ee) {
        int c = counts[ee];
        int nt = (c + 127) >> 7;
        if (rt < tb + nt) { e = ee; rowbase = (rt - tb) << 7; cnt = c; off = osum; break; }
        tb += nt; osum += c;
    }
    if (e < 0) return;
    int s2 = blockIdx.z;

    __shared__ __align__(16) char lds[2][16384];

    int t = threadIdx.x, lane = t & 63, w = t >> 6;
    int wr = w >> 1, wc = w & 1;
    int q = lane >> 4, p = lane & 15;

    const size_t ASTEP = (size_t)4 * NROWA * 16;
    const size_t BSTEP = (size_t)4 * D_EMBED * 16;
    const size_t A2 = (size_t)2 * NROWA * 16;
    const size_t B2 = (size_t)2 * D_EMBED * 16;
    const char* aS = (const char*)hp
        + ((size_t)(s2 * 128 + (t >> 7)) * NROWA + off + rowbase + (t & 127)) * 16;
    const char* bS = (const char*)wt2 + (size_t)e * D_HID * D_EMBED * 2
        + ((size_t)(s2 * 128 + (t >> 7)) * D_EMBED + blockIdx.x * 128 + (t & 127)) * 16;

    int wslot = 0;
    auto STG = [&]() {
        char* L = &lds[wslot][0];
        wslot ^= 1;
        gload_lds16(aS, L + t * 16);
        gload_lds16(aS + A2, L + 4096 + t * 16);
        gload_lds16(bS, L + 8192 + t * 16);
        gload_lds16(bS + B2, L + 12288 + t * 16);
        aS += ASTEP; bS += BSTEP;
    };

    f32x4 acc[4][4] = {};

    STG();
#pragma unroll 1
    for (int h = 0; h < 32; ++h) {                 // 1024 k per split, half-K=32
        if (h < 31) STG();
        if (h < 31) asm volatile("s_waitcnt vmcnt(4)" ::: "memory");
        else        asm volatile("s_waitcnt vmcnt(0)" ::: "memory");
        __builtin_amdgcn_s_barrier();
        __builtin_amdgcn_sched_barrier(0);
        const char* L = &lds[h & 1][0];
        bf16x8 af[4], bf[4];
#pragma unroll
        for (int m = 0; m < 4; ++m)
            af[m] = *reinterpret_cast<const bf16x8*>(L + (q * 128 + wr * 64 + m * 16 + p) * 16);
#pragma unroll
        for (int n = 0; n < 4; ++n)
            bf[n] = *reinterpret_cast<const bf16x8*>(L + 8192 + (q * 128 + wc * 64 + n * 16 + p) * 16);
        __builtin_amdgcn_s_setprio(1);
#pragma unroll
        for (int n = 0; n < 4; ++n)
#pragma unroll
            for (int m = 0; m < 4; ++m)
                acc[m][n] = __builtin_amdgcn_mfma_f32_16x16x32_bf16(af[m], bf[n], acc[m][n], 0, 0, 0);
        __builtin_amdgcn_s_setprio(0);
    }

    unsigned short* pb = pbuf + (size_t)s2 * 8192 * D_EMBED;
#pragma unroll
    for (int m = 0; m < 4; ++m)
#pragma unroll
        for (int reg = 0; reg < 4; ++reg) {
            int rl = wr * 64 + m * 16 + q * 4 + reg;
            int grow = rowbase + rl;
            if (grow >= cnt) continue;
            unsigned short* dst = pb + (size_t)(off + grow) * D_EMBED + blockIdx.x * 128 + wc * 64;
#pragma unroll
            for (int n = 0; n < 4; ++n) dst[n * 16 + p] = f2bf(acc[m][n][reg]);
        }
}

// ---------------- combine: out[tok] = sum over 2 rows x 4 k-splits (bf16 pbuf) ----------------
__global__ __launch_bounds__(256) void combine_kernel(const unsigned short* __restrict__ pbuf,
                                                      const int* __restrict__ tok2row,
                                                      float* __restrict__ out) {
    int i = blockIdx.x * 256 + threadIdx.x;        // N_TOK * 128, 8 cols each
    int tok = i >> 7, c0 = (i & 127) * 8;
    int r0 = tok2row[tok * 2], r1 = tok2row[tok * 2 + 1];
    const size_t SP = (size_t)8192 * D_EMBED;
    float s[8] = {0, 0, 0, 0, 0, 0, 0, 0};
#pragma unroll
    for (int sp = 0; sp < 4; ++sp) {
        bf16x8 a = *reinterpret_cast<const bf16x8*>(pbuf + sp * SP + (size_t)r0 * D_EMBED + c0);
        bf16x8 b = *reinterpret_cast<const bf16x8*>(pbuf + sp * SP + (size_t)r1 * D_EMBED + c0);
#pragma unroll
        for (int j = 0; j < 8; ++j)
            s[j] += bf2f((unsigned short)a[j]) + bf2f((unsigned short)b[j]);
    }
    float* op = out + (size_t)tok * D_EMBED + c0;
    f32x4 lo = {s[0], s[1], s[2], s[3]}, hi = {s[4], s[5], s[6], s[7]};
    *reinterpret_cast<f32x4*>(op) = lo;
    *reinterpret_cast<f32x4*>(op + 4) = hi;
}

extern "C" void kernel_launch(void* const* d_in, const int* in_sizes, int n_in,
                              void* d_out, int out_size, void* d_ws, size_t ws_size,
                              hipStream_t stream) {
    const float* x  = (const float*)d_in[0];
    const float* Wg = (const float*)d_in[1];
    const float* W1 = (const float*)d_in[2];
    const float* W3 = (const float*)d_in[3];
    const float* W2 = (const float*)d_in[4];
    float* out = (float*)d_out;

    char* ws = (char*)d_ws;
    size_t szW = (size_t)N_EXP * D_EMBED * D_HID;
    unsigned short* wt13 = (unsigned short*)ws; ws += szW * 2 * 2;     // 128 MB
    unsigned short* wt2  = (unsigned short*)ws; ws += szW * 2;         // 64 MB
    unsigned short* hp   = (unsigned short*)ws; ws += (size_t)(D_HID / 8) * NROWA * 8 * 2;
    unsigned short* xg   = (unsigned short*)ws; ws += (size_t)(D_EMBED / 8) * NROWA * 8 * 2;
    int*   toks    = (int*)ws;   ws += (size_t)N_EXP * CAP * 4;
    float* wgts    = (float*)ws; ws += (size_t)N_EXP * CAP * 4;
    int*   slots   = (int*)ws;   ws += (size_t)N_EXP * CAP * 4;
    int*   tok2row = (int*)ws;   ws += (size_t)N_TOK * 2 * 4;
    int*   counts  = (int*)ws;   ws += 8 * 4;
    // pbuf bf16 (64 MB: 4 splits x 8192 x 1024) aliases wt13 (dead after gemm1)
    unsigned short* pbuf = (unsigned short*)wt13;

    hipMemsetAsync(counts, 0, 8 * sizeof(int), stream);

    pack_gate_v<<<13312, 256, 0, stream>>>(W1, W3, W2, x, Wg, wt13, wt2,
                                           counts, toks, wgts, slots);
    gather_x_kernel<<<dim3(136, D_EMBED / 64), 256, 0, stream>>>(x, counts, toks, slots, tok2row, xg);
    gemm1_kernel<<<dim3(64, 72), 256, 0, stream>>>(xg, wt13, counts, wgts, hp);
    gemm2_kernel<<<dim3(8, 72, 4), 256, 0, stream>>>(hp, wt2, counts, pbuf);
    combine_kernel<<<(N_TOK * 128) / 256, 256, 0, stream>>>(pbuf, tok2row, out);
}

// Round 19
// 474.687 us; speedup vs baseline: 1.0648x; 1.0234x over previous
//
#include <hip/hip_runtime.h>
#include <hip/hip_bf16.h>
#include <stdint.h>

#define D_EMBED 1024
#define D_HID   4096
#define N_TOK   4096
#define N_EXP   8
#define CAP     4096
#define NROWA   8448

typedef __attribute__((ext_vector_type(4))) float f32x4;
typedef __attribute__((ext_vector_type(8))) short bf16x8;

__device__ __forceinline__ unsigned short f2bf(float f) {
    unsigned int u = __builtin_bit_cast(unsigned int, f);
    u += 0x7fffu + ((u >> 16) & 1u);
    return (unsigned short)(u >> 16);
}
__device__ __forceinline__ float bf2f(unsigned short h) {
    unsigned int u = ((unsigned int)h) << 16;
    return __builtin_bit_cast(float, u);
}
__device__ __forceinline__ void gload_lds16(const void* g, void* l) {
    __builtin_amdgcn_global_load_lds(
        (const __attribute__((address_space(1))) unsigned int*)g,
        (__attribute__((address_space(3))) unsigned int*)l, 16, 0, 0);
}

// ======= merged pack (LDS-transpose, contiguous reads) + gating =======
// blocks [0,16384): wt13 (128 cb x 16 kb x 8 e).
// blocks [16384,24576): wt2 (16 cbw x 64 kb x 8 e).
// blocks [24576,25600): gate (1024).
__global__ __launch_bounds__(256) void pack_gate_t(const float* __restrict__ W1,
                                                   const float* __restrict__ W3,
                                                   const float* __restrict__ W2,
                                                   const float* __restrict__ x,
                                                   const float* __restrict__ Wg,
                                                   unsigned short* __restrict__ wt13,
                                                   unsigned short* __restrict__ wt2,
                                                   int* __restrict__ counts,
                                                   int* __restrict__ toks,
                                                   float* __restrict__ wgts,
                                                   int* __restrict__ slots) {
    int b = blockIdx.x;
    if (b < 16384) {
        // W1|W3 col-interleaved pack: tile = 64 k-rows x (32 W1 cols + 32 W3 cols)
        int cb = b & 127, kb = (b >> 7) & 15, e = b >> 11;    // e < 8
        size_t ebase = (size_t)e * D_EMBED * D_HID;
        const float* b1 = W1 + ebase + (size_t)(kb * 64) * D_HID + cb * 32;
        const float* b3 = W3 + ebase + (size_t)(kb * 64) * D_HID + cb * 32;
        unsigned short* op = wt13 + (size_t)e * D_EMBED * 2 * D_HID;
        __shared__ unsigned short lds[64][72];   // cols: [W1a 16][W1b 16][W3a 16][W3b 16]
        int t = threadIdx.x;
        int r = t >> 2, ck = t & 3;
        const float* src = (ck >= 2 ? b3 : b1) + (size_t)r * D_HID + (ck & 1) * 16;
#pragma unroll
        for (int i = 0; i < 2; ++i) {
            f32x4 a = *reinterpret_cast<const f32x4*>(src + i * 8);
            f32x4 c = *reinterpret_cast<const f32x4*>(src + i * 8 + 4);
            bf16x8 o;
            o[0]=(short)f2bf(a[0]); o[1]=(short)f2bf(a[1]); o[2]=(short)f2bf(a[2]); o[3]=(short)f2bf(a[3]);
            o[4]=(short)f2bf(c[0]); o[5]=(short)f2bf(c[1]); o[6]=(short)f2bf(c[2]); o[7]=(short)f2bf(c[3]);
            *reinterpret_cast<bf16x8*>(&lds[r][ck * 16 + i * 8]) = o;
        }
        __syncthreads();
#pragma unroll
        for (int i = 0; i < 2; ++i) {
            int cell = i * 256 + t;
            int ksl = cell >> 6, pcp = cell & 63;
            int lcol = ((pcp >> 4) & 1) * 32 + ((pcp >> 5) & 1) * 16 + (pcp & 15);
            bf16x8 o;
#pragma unroll
            for (int j = 0; j < 8; ++j) o[j] = (short)lds[ksl * 8 + j][lcol];
            *reinterpret_cast<bf16x8*>(op + ((size_t)(kb * 8 + ksl) * (2 * D_HID) + cb * 64 + pcp) * 8) = o;
        }
    } else if (b < 24576) {
        // W2 pack: tile = 64 k-rows x 64 cols
        int bb = b - 16384;
        int cbw = bb & 15, kb = (bb >> 4) & 63, e = bb >> 10;  // e < 8
        const float* Wp = W2 + (size_t)e * D_HID * D_EMBED + (size_t)(kb * 64) * D_EMBED + cbw * 64;
        unsigned short* op = wt2 + (size_t)e * D_HID * D_EMBED;
        __shared__ unsigned short lds2[64][72];
        int t = threadIdx.x;
        int r = t >> 2, c0 = (t & 3) << 4;
        const float* src = Wp + (size_t)r * D_EMBED + c0;
#pragma unroll
        for (int i = 0; i < 2; ++i) {
            f32x4 a = *reinterpret_cast<const f32x4*>(src + i * 8);
            f32x4 c = *reinterpret_cast<const f32x4*>(src + i * 8 + 4);
            bf16x8 o;
            o[0]=(short)f2bf(a[0]); o[1]=(short)f2bf(a[1]); o[2]=(short)f2bf(a[2]); o[3]=(short)f2bf(a[3]);
            o[4]=(short)f2bf(c[0]); o[5]=(short)f2bf(c[1]); o[6]=(short)f2bf(c[2]); o[7]=(short)f2bf(c[3]);
            *reinterpret_cast<bf16x8*>(&lds2[r][c0 + i * 8]) = o;
        }
        __syncthreads();
#pragma unroll
        for (int i = 0; i < 2; ++i) {
            int cell = i * 256 + t;
            int ksl = cell >> 6, col = cell & 63;
            bf16x8 o;
#pragma unroll
            for (int j = 0; j < 8; ++j) o[j] = (short)lds2[ksl * 8 + j][col];
            *reinterpret_cast<bf16x8*>(op + ((size_t)(kb * 8 + ksl) * D_EMBED + cbw * 64 + col) * 8) = o;
        }
    } else {
        int gb = b - 24576;
        int wave = threadIdx.x >> 6;
        int lane = threadIdx.x & 63;
        int tok = gb * 4 + wave;
        const float* xp = x + (size_t)tok * D_EMBED;
        float acc[8] = {0, 0, 0, 0, 0, 0, 0, 0};
#pragma unroll
        for (int i = 0; i < 16; ++i) {
            int d = lane + 64 * i;
            float xv = xp[d];
            f32x4 w0 = *reinterpret_cast<const f32x4*>(Wg + (size_t)d * 8);
            f32x4 w1 = *reinterpret_cast<const f32x4*>(Wg + (size_t)d * 8 + 4);
            acc[0] += xv * w0[0]; acc[1] += xv * w0[1]; acc[2] += xv * w0[2]; acc[3] += xv * w0[3];
            acc[4] += xv * w1[0]; acc[5] += xv * w1[1]; acc[6] += xv * w1[2]; acc[7] += xv * w1[3];
        }
#pragma unroll
        for (int e = 0; e < 8; ++e)
            for (int s = 32; s; s >>= 1) acc[e] += __shfl_xor(acc[e], s, 64);
        if (lane == 0) {
            int i0 = 0; float v0 = acc[0];
#pragma unroll
            for (int e = 1; e < 8; ++e) if (acc[e] > v0) { v0 = acc[e]; i0 = e; }
            int i1 = -1; float v1 = -1e30f;
#pragma unroll
            for (int e = 0; e < 8; ++e) if (e != i0 && acc[e] > v1) { v1 = acc[e]; i1 = e; }
            float ex = __expf(v1 - v0);
            float w0 = 1.0f / (1.0f + ex);
            float w1 = 1.0f - w0;
            int p0 = atomicAdd(&counts[i0], 1);
            toks[i0 * CAP + p0] = tok; wgts[i0 * CAP + p0] = w0; slots[i0 * CAP + p0] = 0;
            int p1 = atomicAdd(&counts[i1], 1);
            toks[i1 * CAP + p1] = tok; wgts[i1 * CAP + p1] = w1; slots[i1 * CAP + p1] = 1;
        }
    }
}

// ------- gather x rows into compacted k-packed A (tok2row folded in) -------
__global__ __launch_bounds__(256) void gather_x_kernel(
    const float* __restrict__ x, const int* __restrict__ counts,
    const int* __restrict__ toks, const int* __restrict__ slots,
    int* __restrict__ tok2row, unsigned short* __restrict__ xg) {
    int rt = blockIdx.x;
    int e = -1, tb = 0, osum = 0, rowbase = 0, cnt = 0, off = 0;
    for (int ee = 0; ee < N_EXP; ++ee) {
        int c = counts[ee];
        int nt = (c + 63) >> 6;
        if (rt < tb + nt) { e = ee; rowbase = (rt - tb) << 6; cnt = c; off = osum; break; }
        tb += nt; osum += c;
    }
    if (e < 0) return;
    int kb = blockIdx.y;
    int t = threadIdx.x;
    if (kb == 0 && t < 64) {
        int pos = rowbase + t;
        if (pos < cnt) {
            int i = e * CAP + pos;
            tok2row[toks[i] * 2 + slots[i]] = off + pos;
        }
    }
    __shared__ unsigned short lds[64][72];
    int r = t >> 2, ck = t & 3;
    int pos = rowbase + r;
    unsigned short tmp[16];
    if (pos < cnt) {
        int tok = toks[e * CAP + pos];
        const float* src = x + (size_t)tok * D_EMBED + kb * 64 + ck * 16;
#pragma unroll
        for (int i = 0; i < 4; ++i) {
            f32x4 v = *reinterpret_cast<const f32x4*>(src + i * 4);
#pragma unroll
            for (int j = 0; j < 4; ++j) tmp[i * 4 + j] = f2bf(v[j]);
        }
    } else {
#pragma unroll
        for (int i = 0; i < 16; ++i) tmp[i] = 0;
    }
#pragma unroll
    for (int i = 0; i < 16; ++i) lds[r][ck * 16 + i] = tmp[i];
    __syncthreads();
    int sl = t >> 5, rr = (t & 31) * 2;
#pragma unroll
    for (int w = 0; w < 2; ++w) {
        int rw = rr + w;
        if (rowbase + rw >= cnt) continue;
        bf16x8 o;
#pragma unroll
        for (int j = 0; j < 8; ++j) o[j] = (short)lds[rw][sl * 8 + j];
        *reinterpret_cast<bf16x8*>(xg + ((size_t)(kb * 8 + sl) * NROWA + off + rowbase + rw) * 8) = o;
    }
}

// ======= GEMM1: 128x128p, 4 waves (2Mx2N), ring-2 half-K(32), vmcnt(4) =======
// grid (x = packed coltile 64, y = rowtile 72): XCD = x%8 -> B panel pinned per XCD
__global__ __launch_bounds__(256, 4) void gemm1_kernel(
    const unsigned short* __restrict__ xg,
    const unsigned short* __restrict__ wt13,
    const int* __restrict__ counts,
    const float* __restrict__ wgts,
    unsigned short* __restrict__ hp) {
    int rt = blockIdx.y;
    int e = -1, tb = 0, osum = 0, rowbase = 0, cnt = 0, off = 0;
#pragma unroll 1
    for (int ee = 0; ee < N_EXP; ++ee) {
        int c = counts[ee];
        int nt = (c + 127) >> 7;
        if (rt < tb + nt) { e = ee; rowbase = (rt - tb) << 7; cnt = c; off = osum; break; }
        tb += nt; osum += c;
    }
    if (e < 0) return;

    __shared__ __align__(16) char lds[2][16384];   // slot: A 8K | B 8K

    int t = threadIdx.x, lane = t & 63, w = t >> 6;   // 4 waves, 2Mx2N
    int wr = w >> 1, wc = w & 1;
    int q = lane >> 4, p = lane & 15;

    const size_t ASTEP = (size_t)4 * NROWA * 16;
    const size_t BSTEP = (size_t)4 * (2 * D_HID) * 16;
    const size_t A2 = (size_t)2 * NROWA * 16;
    const size_t B2 = (size_t)2 * (2 * D_HID) * 16;
    const char* aS = (const char*)xg + ((size_t)(t >> 7) * NROWA + off + rowbase + (t & 127)) * 16;
    const char* bS = (const char*)wt13 + (size_t)e * D_EMBED * 2 * D_HID * 2
                   + ((size_t)(t >> 7) * (2 * D_HID) + blockIdx.x * 128 + (t & 127)) * 16;

    int wslot = 0;
    auto STG = [&]() {
        char* L = &lds[wslot][0];
        wslot ^= 1;
        gload_lds16(aS, L + t * 16);
        gload_lds16(aS + A2, L + 4096 + t * 16);
        gload_lds16(bS, L + 8192 + t * 16);
        gload_lds16(bS + B2, L + 12288 + t * 16);
        aS += ASTEP; bS += BSTEP;
    };

    f32x4 acc[4][4] = {};

    STG();
#pragma unroll 1
    for (int h = 0; h < 32; ++h) {                 // K=1024, half-K=32
        if (h < 31) STG();
        if (h < 31) asm volatile("s_waitcnt vmcnt(4)" ::: "memory");
        else        asm volatile("s_waitcnt vmcnt(0)" ::: "memory");
        __builtin_amdgcn_s_barrier();
        __builtin_amdgcn_sched_barrier(0);
        const char* L = &lds[h & 1][0];
        bf16x8 af[4], bf[4];
#pragma unroll
        for (int m = 0; m < 4; ++m)
            af[m] = *reinterpret_cast<const bf16x8*>(L + (q * 128 + wr * 64 + m * 16 + p) * 16);
#pragma unroll
        for (int n = 0; n < 4; ++n)
            bf[n] = *reinterpret_cast<const bf16x8*>(L + 8192 + (q * 128 + wc * 64 + n * 16 + p) * 16);
        __builtin_amdgcn_s_setprio(1);
#pragma unroll
        for (int n = 0; n < 4; ++n)
#pragma unroll
            for (int m = 0; m < 4; ++m)
                acc[m][n] = __builtin_amdgcn_mfma_f32_16x16x32_bf16(af[m], bf[n], acc[m][n], 0, 0, 0);
        __builtin_amdgcn_s_setprio(0);
    }

    // epilogue: (even n = W1, odd n = W3) -> SwiGLU * gate-weight -> hp (k-packed)
#pragma unroll
    for (int m = 0; m < 4; ++m) {
#pragma unroll
        for (int reg = 0; reg < 4; ++reg) {
            int rl = wr * 64 + m * 16 + q * 4 + reg;
            int grow = rowbase + rl;
            if (grow >= cnt) continue;
            float wgt = wgts[e * CAP + grow];
            size_t row = (size_t)(off + grow);
#pragma unroll
            for (int np = 0; np < 2; ++np) {
                float a1 = acc[m][2 * np][reg];
                float a3 = acc[m][2 * np + 1][reg];
                float hv = (a1 / (1.0f + __expf(-a1))) * a3 * wgt;
                int rc = (blockIdx.x * 4 + wc * 2 + np) * 16 + p;
                hp[((size_t)(rc >> 3) * NROWA + row) * 8 + (rc & 7)] = f2bf(hv);
            }
        }
    }
}

// ======= GEMM2: 128x128, 4 waves, split-K=2, ring-2 vmcnt(4) =======
// grid (x = coltile 8, y = rowtile 72, z = split 2): XCD = x -> B col panel pinned
__global__ __launch_bounds__(256, 4) void gemm2_kernel(
    const unsigned short* __restrict__ hp,
    const unsigned short* __restrict__ wt2,
    const int* __restrict__ counts,
    unsigned short* __restrict__ pbuf) {
    int rt = blockIdx.y;
    int e = -1, tb = 0, osum = 0, rowbase = 0, cnt = 0, off = 0;
#pragma unroll 1
    for (int ee = 0; ee < N_EXP; ++ee) {
        int c = counts[ee];
        int nt = (c + 127) >> 7;
        if (rt < tb + nt) { e = ee; rowbase = (rt - tb) << 7; cnt = c; off = osum; break; }
        tb += nt; osum += c;
    }
    if (e < 0) return;
    int s2 = blockIdx.z;

    __shared__ __align__(16) char lds[2][16384];

    int t = threadIdx.x, lane = t & 63, w = t >> 6;
    int wr = w >> 1, wc = w & 1;
    int q = lane >> 4, p = lane & 15;

    const size_t ASTEP = (size_t)4 * NROWA * 16;
    const size_t BSTEP = (size_t)4 * D_EMBED * 16;
    const size_t A2 = (size_t)2 * NROWA * 16;
    const size_t B2 = (size_t)2 * D_EMBED * 16;
    const char* aS = (const char*)hp
        + ((size_t)(s2 * 256 + (t >> 7)) * NROWA + off + rowbase + (t & 127)) * 16;
    const char* bS = (const char*)wt2 + (size_t)e * D_HID * D_EMBED * 2
        + ((size_t)(s2 * 256 + (t >> 7)) * D_EMBED + blockIdx.x * 128 + (t & 127)) * 16;

    int wslot = 0;
    auto STG = [&]() {
        char* L = &lds[wslot][0];
        wslot ^= 1;
        gload_lds16(aS, L + t * 16);
        gload_lds16(aS + A2, L + 4096 + t * 16);
        gload_lds16(bS, L + 8192 + t * 16);
        gload_lds16(bS + B2, L + 12288 + t * 16);
        aS += ASTEP; bS += BSTEP;
    };

    f32x4 acc[4][4] = {};

    STG();
#pragma unroll 1
    for (int h = 0; h < 64; ++h) {                 // 2048 k per split, half-K=32
        if (h < 63) STG();
        if (h < 63) asm volatile("s_waitcnt vmcnt(4)" ::: "memory");
        else        asm volatile("s_waitcnt vmcnt(0)" ::: "memory");
        __builtin_amdgcn_s_barrier();
        __builtin_amdgcn_sched_barrier(0);
        const char* L = &lds[h & 1][0];
        bf16x8 af[4], bf[4];
#pragma unroll
        for (int m = 0; m < 4; ++m)
            af[m] = *reinterpret_cast<const bf16x8*>(L + (q * 128 + wr * 64 + m * 16 + p) * 16);
#pragma unroll
        for (int n = 0; n < 4; ++n)
            bf[n] = *reinterpret_cast<const bf16x8*>(L + 8192 + (q * 128 + wc * 64 + n * 16 + p) * 16);
        __builtin_amdgcn_s_setprio(1);
#pragma unroll
        for (int n = 0; n < 4; ++n)
#pragma unroll
            for (int m = 0; m < 4; ++m)
                acc[m][n] = __builtin_amdgcn_mfma_f32_16x16x32_bf16(af[m], bf[n], acc[m][n], 0, 0, 0);
        __builtin_amdgcn_s_setprio(0);
    }

    unsigned short* pb = pbuf + (size_t)s2 * 8192 * D_EMBED;
#pragma unroll
    for (int m = 0; m < 4; ++m)
#pragma unroll
        for (int reg = 0; reg < 4; ++reg) {
            int rl = wr * 64 + m * 16 + q * 4 + reg;
            int grow = rowbase + rl;
            if (grow >= cnt) continue;
            unsigned short* dst = pb + (size_t)(off + grow) * D_EMBED + blockIdx.x * 128 + wc * 64;
#pragma unroll
            for (int n = 0; n < 4; ++n) dst[n * 16 + p] = f2bf(acc[m][n][reg]);
        }
}

// ---------------- combine: out[tok] = sum over 2 rows x 2 k-splits (bf16 pbuf) ----------------
__global__ __launch_bounds__(256) void combine_kernel(const unsigned short* __restrict__ pbuf,
                                                      const int* __restrict__ tok2row,
                                                      float* __restrict__ out) {
    int i = blockIdx.x * 256 + threadIdx.x;        // N_TOK * 128, 8 cols each
    int tok = i >> 7, c0 = (i & 127) * 8;
    int r0 = tok2row[tok * 2], r1 = tok2row[tok * 2 + 1];
    const size_t SP = (size_t)8192 * D_EMBED;
    float s[8] = {0, 0, 0, 0, 0, 0, 0, 0};
#pragma unroll
    for (int sp = 0; sp < 2; ++sp) {
        bf16x8 a = *reinterpret_cast<const bf16x8*>(pbuf + sp * SP + (size_t)r0 * D_EMBED + c0);
        bf16x8 b = *reinterpret_cast<const bf16x8*>(pbuf + sp * SP + (size_t)r1 * D_EMBED + c0);
#pragma unroll
        for (int j = 0; j < 8; ++j)
            s[j] += bf2f((unsigned short)a[j]) + bf2f((unsigned short)b[j]);
    }
    float* op = out + (size_t)tok * D_EMBED + c0;
    f32x4 lo = {s[0], s[1], s[2], s[3]}, hi = {s[4], s[5], s[6], s[7]};
    *reinterpret_cast<f32x4*>(op) = lo;
    *reinterpret_cast<f32x4*>(op + 4) = hi;
}

extern "C" void kernel_launch(void* const* d_in, const int* in_sizes, int n_in,
                              void* d_out, int out_size, void* d_ws, size_t ws_size,
                              hipStream_t stream) {
    const float* x  = (const float*)d_in[0];
    const float* Wg = (const float*)d_in[1];
    const float* W1 = (const float*)d_in[2];
    const float* W3 = (const float*)d_in[3];
    const float* W2 = (const float*)d_in[4];
    float* out = (float*)d_out;

    char* ws = (char*)d_ws;
    size_t szW = (size_t)N_EXP * D_EMBED * D_HID;
    unsigned short* wt13 = (unsigned short*)ws; ws += szW * 2 * 2;     // 128 MB
    unsigned short* wt2  = (unsigned short*)ws; ws += szW * 2;         // 64 MB
    unsigned short* hp   = (unsigned short*)ws; ws += (size_t)(D_HID / 8) * NROWA * 8 * 2;
    unsigned short* xg   = (unsigned short*)ws; ws += (size_t)(D_EMBED / 8) * NROWA * 8 * 2;
    int*   toks    = (int*)ws;   ws += (size_t)N_EXP * CAP * 4;
    float* wgts    = (float*)ws; ws += (size_t)N_EXP * CAP * 4;
    int*   slots   = (int*)ws;   ws += (size_t)N_EXP * CAP * 4;
    int*   tok2row = (int*)ws;   ws += (size_t)N_TOK * 2 * 4;
    int*   counts  = (int*)ws;   ws += 8 * 4;
    // pbuf bf16 (32 MB: 2 splits x 8192 x 1024) aliases wt13 (dead after gemm1)
    unsigned short* pbuf = (unsigned short*)wt13;

    hipMemsetAsync(counts, 0, 8 * sizeof(int), stream);

    pack_gate_t<<<25600, 256, 0, stream>>>(W1, W3, W2, x, Wg, wt13, wt2,
                                           counts, toks, wgts, slots);
    gather_x_kernel<<<dim3(136, D_EMBED / 64), 256, 0, stream>>>(x, counts, toks, slots, tok2row, xg);
    gemm1_kernel<<<dim3(64, 72), 256, 0, stream>>>(xg, wt13, counts, wgts, hp);
    gemm2_kernel<<<dim3(8, 72, 2), 256, 0, stream>>>(hp, wt2, counts, pbuf);
    combine_kernel<<<(N_TOK * 128) / 256, 256, 0, stream>>>(pbuf, tok2row, out);
}